// Round 2
// baseline (30461.948 us; speedup 1.0000x reference)
//
#include <hip/hip_runtime.h>
#include <hip/hip_fp16.h>
#include <cstdint>

// LSTMNet: embed(128->512) -> 3x LSTM(512) -> decode last step.
// B=256, T=256. f16 MFMA (16x16x32), fp32 accum, fp32 cell state.
//
// Persistent recurrent kernel: 256 blocks = 8 batch-groups (32 rows, XCD-aligned
// via blockIdx%8) x 32 hidden-parts (16 units). Per block: fused [w_ih|w_hh]
// slice (64 gcols x 1024 K f16 = 128KB) resident in LDS across all timesteps.
// Per step: 4 waves split K, MFMA into fp32, reduce partials via 16KB LDS,
// gates in fp32, c in registers, h written f16 to ping-pong act buffer.
// 32-block group barrier per step: agent-scope flags + __threadfence().
// Launched via hipLaunchCooperativeKernel (guaranteed co-residency); spins are
// guarded (timeout -> give up, wrong answer but no GPU wedge).

#define TSEQ 256
#define NBAT 256
#define DIN  128
#define HID  512
#define NL   3

typedef _Float16 half_t;
typedef __attribute__((ext_vector_type(8))) _Float16 half8;
typedef __attribute__((ext_vector_type(4))) _Float16 half4v;
typedef __attribute__((ext_vector_type(4))) float f32x4;

__device__ __forceinline__ float sigmoidf_(float x) {
    return 1.f / (1.f + __expf(-x));
}
__device__ __forceinline__ float tanhf_(float x) {
    float xc = fminf(fmaxf(x, -15.f), 15.f);
    float e = __expf(2.f * xc);
    return (e - 1.f) / (e + 1.f);
}

// ---------------- embed: out[t][b][j] = f16( x[b][t][:] . W[j][:] + bias[j] )
// grid 1024: block covers 64 out-rows (fixed t, 64 b). LDS: x-tile 16KB + W 128KB (swizzled).
__global__ __launch_bounds__(256) void k_embed(const float* __restrict__ x,
                                               const float* __restrict__ W,
                                               const float* __restrict__ bias,
                                               half_t* __restrict__ out) {
    extern __shared__ char smem[];
    half_t* Xs = (half_t*)smem;            // [64][128] swizzled
    half_t* Ws = (half_t*)(smem + 16384);  // [512][128] swizzled
    const int tid = threadIdx.x;
    const int bk = blockIdx.x;
    const int t = bk >> 2, b0 = (bk & 3) << 6;

    // stage x tile 64x128 -> f16 LDS
    #pragma unroll
    for (int it = 0; it < 8; ++it) {
        int idx = tid + (it << 8);               // 2048 float4 units
        int r = idx >> 5, k = (idx & 31) << 2;
        float4 v = *(const float4*)(x + ((size_t)(b0 + r) * TSEQ + t) * DIN + k);
        half4v hv = {(half_t)v.x, (half_t)v.y, (half_t)v.z, (half_t)v.w};
        int byte = r * 256 + ((k * 2) ^ ((r & 7) << 4));
        *(half4v*)((char*)Xs + byte) = hv;
    }
    // stage W 512x128 -> f16 LDS
    #pragma unroll 4
    for (int it = 0; it < 64; ++it) {
        int idx = tid + (it << 8);               // 16384 float4 units
        int r = idx >> 5, k = (idx & 31) << 2;
        float4 v = *(const float4*)(W + (size_t)r * DIN + k);
        half4v hv = {(half_t)v.x, (half_t)v.y, (half_t)v.z, (half_t)v.w};
        int byte = r * 256 + ((k * 2) ^ ((r & 7) << 4));
        *(half4v*)((char*)Ws + byte) = hv;
    }
    __syncthreads();

    const int lane = tid & 63, wv = tid >> 6;
    f32x4 acc[4][8];
    #pragma unroll
    for (int m = 0; m < 4; ++m)
        #pragma unroll
        for (int n = 0; n < 8; ++n) acc[m][n] = (f32x4){0.f, 0.f, 0.f, 0.f};

    #pragma unroll
    for (int kit = 0; kit < 4; ++kit) {
        int kk = (kit << 5) + ((lane >> 4) << 3);
        half8 a[4];
        #pragma unroll
        for (int m = 0; m < 4; ++m) {
            int r = (m << 4) + (lane & 15);
            int byte = r * 256 + ((kk * 2) ^ ((r & 7) << 4));
            a[m] = *(half8*)((char*)Xs + byte);
        }
        #pragma unroll
        for (int n = 0; n < 8; ++n) {
            int r = (wv << 7) + (n << 4) + (lane & 15);
            int byte = r * 256 + ((kk * 2) ^ ((r & 7) << 4));
            half8 b = *(half8*)((char*)Ws + byte);
            #pragma unroll
            for (int m = 0; m < 4; ++m)
                acc[m][n] = __builtin_amdgcn_mfma_f32_16x16x32_f16(a[m], b, acc[m][n], 0, 0, 0);
        }
    }
    __syncthreads();
    // D-frag (col=lane&15, row=(lane>>4)*4+reg) -> LDS [64][512] f16, + bias
    half_t* Os = (half_t*)smem;
    #pragma unroll
    for (int n = 0; n < 8; ++n) {
        int j = (wv << 7) + (n << 4) + (lane & 15);
        float bj = bias[j];
        #pragma unroll
        for (int m = 0; m < 4; ++m)
            #pragma unroll
            for (int r = 0; r < 4; ++r) {
                int mr = (m << 4) + ((lane >> 4) << 2) + r;
                Os[mr * 512 + j] = (half_t)(acc[m][n][r] + bj);
            }
    }
    __syncthreads();
    // coalesced f16 store
    #pragma unroll
    for (int it = 0; it < 16; ++it) {
        int idx = tid + (it << 8);               // 4096 half8 units
        int r = idx >> 6, c = (idx & 63) << 3;
        half8 v = *(half8*)(Os + r * 512 + c);
        *(half8*)(out + ((size_t)t * NBAT + (b0 + r)) * HID + c) = v;
    }
}

// ---------------- persistent recurrent kernel (all 3 layers, 256 steps each)
__global__ __launch_bounds__(256) void k_rec(const float* __restrict__ w_ih,
                                             const float* __restrict__ w_hh,
                                             const float* __restrict__ b_ih,
                                             const float* __restrict__ b_hh,
                                             half_t* __restrict__ bufA,
                                             half_t* __restrict__ bufB,
                                             int* __restrict__ flags) {
    extern __shared__ char smem[];
    half_t* Wl = (half_t*)smem;               // [64][1024] f16 swizzled = 128KB
    float* Pl = (float*)(smem + 131072);      // [4][16][64] partials = 16KB
    const int tid = threadIdx.x;
    const int lane = tid & 63, wv = tid >> 6;
    const int g = blockIdx.x & 7;             // batch group (XCD-aligned)
    const int hb = blockIdx.x >> 3;           // hidden part 0..31
    const int b0 = g << 5;                    // 32 batch rows
    const int j0 = hb << 4;                   // 16 hidden units
    int* myflag = flags + (g << 5) + hb;
    int* grpflags = flags + (g << 5);

    const int rr = tid >> 4;                  // reduce row 0..15
    const int jj = tid & 15;                  // reduce unit 0..15
    float c0 = 0.f, c1 = 0.f;
    float bias[4];
    bool dead = false;                        // spin-guard tripped: stop waiting

    for (int l = 0; l < NL; ++l) {
        const half_t* inb = (l & 1) ? bufB : bufA;
        half_t* outb = (l & 1) ? bufA : bufB;

        __syncthreads();  // previous layer's LDS reads done before overwrite
        {   // stage this layer's fused weight slice: rows=64 gcols, K=1024 (ih|hh)
            int row = tid >> 2;               // 0..63
            int q = tid & 3;                  // K quarter
            int gt = row >> 4, u = row & 15;
            size_t grow = (size_t)l * 2048 + gt * HID + (j0 + u);
            const float* src = (q < 2) ? (w_ih + grow * HID + (q << 8))
                                       : (w_hh + grow * HID + ((q - 2) << 8));
            int kbase = q << 8;
            #pragma unroll 8
            for (int i = 0; i < 64; ++i) {
                float4 v = *(const float4*)(src + (i << 2));
                int k = kbase + (i << 2);
                int byte = row * 2048 + ((k * 2) ^ ((row & 7) << 4));
                half4v hv = {(half_t)v.x, (half_t)v.y, (half_t)v.z, (half_t)v.w};
                *(half4v*)((char*)Wl + byte) = hv;
            }
        }
        #pragma unroll
        for (int gt = 0; gt < 4; ++gt)
            bias[gt] = b_ih[(size_t)l * 2048 + gt * HID + j0 + jj] +
                       b_hh[(size_t)l * 2048 + gt * HID + j0 + jj];
        c0 = c1 = 0.f;
        __syncthreads();

        for (int t = 0; t < TSEQ; ++t) {
            const int epoch = (l << 8) + t;
            // acquire: wait for all 32 peers to finish previous step (guarded)
            if (tid < 32 && !dead) {
                int guard = 0;
                while (__hip_atomic_load(grpflags + tid, __ATOMIC_RELAXED,
                                         __HIP_MEMORY_SCOPE_AGENT) < epoch) {
                    __builtin_amdgcn_s_sleep(2);
                    if (++guard > (1 << 20)) { dead = true; break; }
                }
            }
            __syncthreads();
            __threadfence();  // acquire side: make peers' h visible

            // GEMM: g[32 x 64gcols] = X[32 x 1024] . Wl^T, wave wv owns K-chunk
            f32x4 acc[2][4];
            #pragma unroll
            for (int m = 0; m < 2; ++m)
                #pragma unroll
                for (int n = 0; n < 4; ++n) acc[m][n] = (f32x4){0.f, 0.f, 0.f, 0.f};
            const bool hpart = (wv >= 2);
            if (!hpart || t > 0) {
                const int kc = wv << 8;
                const half_t* base = hpart
                    ? (outb + ((size_t)(t - 1) * NBAT) * HID + (kc - 512))
                    : (inb + ((size_t)t * NBAT) * HID + kc);
                const half_t* ar = base + (size_t)(b0 + (lane & 15)) * HID + ((lane >> 4) << 3);
                #pragma unroll
                for (int kit = 0; kit < 8; ++kit) {
                    half8 a0 = *(const half8*)(ar + (kit << 5));
                    half8 a1 = *(const half8*)(ar + 16 * HID + (kit << 5));
                    #pragma unroll
                    for (int n = 0; n < 4; ++n) {
                        int row = (n << 4) + (lane & 15);
                        int k = kc + (kit << 5) + ((lane >> 4) << 3);
                        int byte = row * 2048 + ((k * 2) ^ ((row & 7) << 4));
                        half8 b = *(const half8*)((char*)Wl + byte);
                        acc[0][n] = __builtin_amdgcn_mfma_f32_16x16x32_f16(a0, b, acc[0][n], 0, 0, 0);
                        acc[1][n] = __builtin_amdgcn_mfma_f32_16x16x32_f16(a1, b, acc[1][n], 0, 0, 0);
                    }
                }
            }

            // reduce + gates, two 16-row phases (Pl = 16KB)
            #pragma unroll
            for (int ph = 0; ph < 2; ++ph) {
                __syncthreads();
                #pragma unroll
                for (int n = 0; n < 4; ++n)
                    #pragma unroll
                    for (int r = 0; r < 4; ++r)
                        Pl[(wv * 16 + ((lane >> 4) << 2) + r) * 64 + (n << 4) + (lane & 15)] =
                            acc[ph][n][r];
                __syncthreads();
                float gs[4];
                #pragma unroll
                for (int gt = 0; gt < 4; ++gt) {
                    float s = bias[gt];
                    #pragma unroll
                    for (int w2 = 0; w2 < 4; ++w2)
                        s += Pl[(w2 * 16 + rr) * 64 + (gt << 4) + jj];
                    gs[gt] = s;
                }
                float ig = sigmoidf_(gs[0]);
                float fg = sigmoidf_(gs[1]);
                float gg = tanhf_(gs[2]);
                float og = sigmoidf_(gs[3]);
                float& cc = ph ? c1 : c0;
                cc = fg * cc + ig * gg;
                float h = og * tanhf_(cc);
                outb[((size_t)t * NBAT + (b0 + (ph << 4) + rr)) * HID + (j0 + jj)] = (half_t)h;
            }
            // release: drain writes, then bump flag (agent scope for cross-XCD)
            __threadfence();
            __syncthreads();
            if (tid == 0)
                __hip_atomic_store(myflag, epoch + 1, __ATOMIC_RELEASE,
                                   __HIP_MEMORY_SCOPE_AGENT);
        }
    }
}

// ---------------- decoder: out[b] = act[T-1][b][:] . dec_W + dec_b
__global__ __launch_bounds__(256) void k_dec(const half_t* __restrict__ act,
                                             const float* __restrict__ dW,
                                             const float* __restrict__ db,
                                             float* __restrict__ out) {
    int tid = threadIdx.x;
    int bl = tid >> 3, part = tid & 7;
    int b = (blockIdx.x << 5) + bl;
    const half_t* row = act + ((size_t)(TSEQ - 1) * NBAT + b) * HID + (part << 6);
    float s = 0.f;
    #pragma unroll
    for (int i = 0; i < 8; ++i) {
        half8 v = *(const half8*)(row + (i << 3));
        const float* wp = dW + (part << 6) + (i << 3);
        #pragma unroll
        for (int u = 0; u < 8; ++u) s += (float)v[u] * wp[u];
    }
    #pragma unroll
    for (int off = 1; off < 8; off <<= 1) s += __shfl_xor(s, off, 64);
    if (part == 0) out[b] = s + db[0];
}

extern "C" void kernel_launch(void* const* d_in, const int* in_sizes, int n_in,
                              void* d_out, int out_size, void* d_ws, size_t ws_size,
                              hipStream_t stream) {
    const float* x = (const float*)d_in[0];
    const float* eW = (const float*)d_in[1];
    const float* eb = (const float*)d_in[2];
    const float* wih = (const float*)d_in[3];
    const float* whh = (const float*)d_in[4];
    const float* bih = (const float*)d_in[5];
    const float* bhh = (const float*)d_in[6];
    const float* dW = (const float*)d_in[7];
    const float* db = (const float*)d_in[8];
    float* out = (float*)d_out;

    const size_t BUF = (size_t)TSEQ * NBAT * HID * sizeof(half_t);  // 64 MB
    if (ws_size < 2 * BUF + 4096) return;  // insufficient workspace: fail loudly

    char* ws = (char*)d_ws;
    half_t* bufA = (half_t*)ws;
    half_t* bufB = (half_t*)(ws + BUF);
    int* flags = (int*)(ws + 2 * BUF);

    hipMemsetAsync(flags, 0, 256 * sizeof(int), stream);

    (void)hipFuncSetAttribute((const void*)k_embed,
                              hipFuncAttributeMaxDynamicSharedMemorySize, 147456);
    (void)hipFuncSetAttribute((const void*)k_rec,
                              hipFuncAttributeMaxDynamicSharedMemorySize, 147456);

    k_embed<<<1024, 256, 147456, stream>>>(x, eW, eb, bufA);

    void* args[] = { (void*)&wih, (void*)&whh, (void*)&bih, (void*)&bhh,
                     (void*)&bufA, (void*)&bufB, (void*)&flags };
    hipError_t ce = hipLaunchCooperativeKernel((const void*)k_rec, dim3(256), dim3(256),
                                               args, 147456, stream);
    if (ce != hipSuccess) {
        // fallback: normal launch; spin guards prevent a wedge if not co-resident
        k_rec<<<256, 256, 147456, stream>>>(wih, whh, bih, bhh, bufA, bufB, flags);
    }

    k_dec<<<8, 256, 0, stream>>>(bufB, dW, db, out);
}

// Round 3
// 4563.027 us; speedup vs baseline: 6.6758x; 6.6758x over previous
//
#include <hip/hip_runtime.h>
#include <hip/hip_fp16.h>
#include <cstdint>

// LSTMNet: embed(128->512) -> 3x LSTM(512) -> decode last step.
// B=256, T=256. f16 MFMA (16x16x32), fp32 accum, fp32 cell state.
//
// Persistent recurrent kernel: 256 blocks = 8 batch-groups (32 rows, XCD-aligned
// via blockIdx&7) x 32 hidden-parts (16 units). Per block: fused [w_ih|w_hh]
// slice (64 gcols x 1024 K f16 = 128KB) resident in LDS across all timesteps.
//
// Cross-block coherence WITHOUT cache-walk fences: every activation access
// (X loads, h loads, h stores, decoder reads) is a relaxed AGENT-scope atomic
// (compiles to sc0 sc1 = L1/L2 bypass, coherent at Infinity Cache). Flag
// barrier: own s_waitcnt vmcnt(0) + relaxed flag store; peers poll relaxed.
// No __threadfence() anywhere in the step loop.

#define TSEQ 256
#define NBAT 256
#define DIN  128
#define HID  512
#define NL   3

typedef _Float16 half_t;
typedef __attribute__((ext_vector_type(8))) _Float16 half8;
typedef __attribute__((ext_vector_type(4))) _Float16 half4v;
typedef __attribute__((ext_vector_type(4))) float f32x4;

__device__ __forceinline__ float sigmoidf_(float x) {
    return 1.f / (1.f + __expf(-x));
}
__device__ __forceinline__ float tanhf_(float x) {
    float xc = fminf(fmaxf(x, -15.f), 15.f);
    float e = __expf(2.f * xc);
    return (e - 1.f) / (e + 1.f);
}

// coherent (agent-scope, cache-bypass) 16B load of activation data
__device__ __forceinline__ half8 ld_cg16(const half_t* p) {
    union { unsigned long long u[2]; half8 v; } r;
    r.u[0] = __hip_atomic_load((const unsigned long long*)p,
                               __ATOMIC_RELAXED, __HIP_MEMORY_SCOPE_AGENT);
    r.u[1] = __hip_atomic_load((const unsigned long long*)p + 1,
                               __ATOMIC_RELAXED, __HIP_MEMORY_SCOPE_AGENT);
    return r.v;
}
// coherent 2B store of one h value
__device__ __forceinline__ void st_cg2(half_t* p, float v) {
    half_t h = (half_t)v;
    unsigned short b = __builtin_bit_cast(unsigned short, h);
    __hip_atomic_store((unsigned short*)p, b,
                       __ATOMIC_RELAXED, __HIP_MEMORY_SCOPE_AGENT);
}

// ---------------- embed: out[t][b][j] = f16( x[b][t][:] . W[j][:] + bias[j] )
__global__ __launch_bounds__(256) void k_embed(const float* __restrict__ x,
                                               const float* __restrict__ W,
                                               const float* __restrict__ bias,
                                               half_t* __restrict__ out) {
    extern __shared__ char smem[];
    half_t* Xs = (half_t*)smem;            // [64][128] swizzled
    half_t* Ws = (half_t*)(smem + 16384);  // [512][128] swizzled
    const int tid = threadIdx.x;
    const int bk = blockIdx.x;
    const int t = bk >> 2, b0 = (bk & 3) << 6;

    #pragma unroll
    for (int it = 0; it < 8; ++it) {
        int idx = tid + (it << 8);
        int r = idx >> 5, k = (idx & 31) << 2;
        float4 v = *(const float4*)(x + ((size_t)(b0 + r) * TSEQ + t) * DIN + k);
        half4v hv = {(half_t)v.x, (half_t)v.y, (half_t)v.z, (half_t)v.w};
        int byte = r * 256 + ((k * 2) ^ ((r & 7) << 4));
        *(half4v*)((char*)Xs + byte) = hv;
    }
    #pragma unroll 4
    for (int it = 0; it < 64; ++it) {
        int idx = tid + (it << 8);
        int r = idx >> 5, k = (idx & 31) << 2;
        float4 v = *(const float4*)(W + (size_t)r * DIN + k);
        half4v hv = {(half_t)v.x, (half_t)v.y, (half_t)v.z, (half_t)v.w};
        int byte = r * 256 + ((k * 2) ^ ((r & 7) << 4));
        *(half4v*)((char*)Ws + byte) = hv;
    }
    __syncthreads();

    const int lane = tid & 63, wv = tid >> 6;
    f32x4 acc[4][8];
    #pragma unroll
    for (int m = 0; m < 4; ++m)
        #pragma unroll
        for (int n = 0; n < 8; ++n) acc[m][n] = (f32x4){0.f, 0.f, 0.f, 0.f};

    #pragma unroll
    for (int kit = 0; kit < 4; ++kit) {
        int kk = (kit << 5) + ((lane >> 4) << 3);
        half8 a[4];
        #pragma unroll
        for (int m = 0; m < 4; ++m) {
            int r = (m << 4) + (lane & 15);
            int byte = r * 256 + ((kk * 2) ^ ((r & 7) << 4));
            a[m] = *(half8*)((char*)Xs + byte);
        }
        #pragma unroll
        for (int n = 0; n < 8; ++n) {
            int r = (wv << 7) + (n << 4) + (lane & 15);
            int byte = r * 256 + ((kk * 2) ^ ((r & 7) << 4));
            half8 b = *(half8*)((char*)Ws + byte);
            #pragma unroll
            for (int m = 0; m < 4; ++m)
                acc[m][n] = __builtin_amdgcn_mfma_f32_16x16x32_f16(a[m], b, acc[m][n], 0, 0, 0);
        }
    }
    __syncthreads();
    half_t* Os = (half_t*)smem;
    #pragma unroll
    for (int n = 0; n < 8; ++n) {
        int j = (wv << 7) + (n << 4) + (lane & 15);
        float bj = bias[j];
        #pragma unroll
        for (int m = 0; m < 4; ++m)
            #pragma unroll
            for (int r = 0; r < 4; ++r) {
                int mr = (m << 4) + ((lane >> 4) << 2) + r;
                Os[mr * 512 + j] = (half_t)(acc[m][n][r] + bj);
            }
    }
    __syncthreads();
    #pragma unroll
    for (int it = 0; it < 16; ++it) {
        int idx = tid + (it << 8);
        int r = idx >> 6, c = (idx & 63) << 3;
        half8 v = *(half8*)(Os + r * 512 + c);
        *(half8*)(out + ((size_t)t * NBAT + (b0 + r)) * HID + c) = v;
    }
}

// ---------------- persistent recurrent kernel (all 3 layers, 256 steps each)
__global__ __launch_bounds__(256) void k_rec(const float* __restrict__ w_ih,
                                             const float* __restrict__ w_hh,
                                             const float* __restrict__ b_ih,
                                             const float* __restrict__ b_hh,
                                             half_t* __restrict__ bufA,
                                             half_t* __restrict__ bufB,
                                             int* __restrict__ flags) {
    extern __shared__ char smem[];
    half_t* Wl = (half_t*)smem;               // [64][1024] f16 swizzled = 128KB
    float* Pl = (float*)(smem + 131072);      // [4*16][64] partials, XOR-swizzled
    const int tid = threadIdx.x;
    const int lane = tid & 63, wv = tid >> 6;
    const int g = blockIdx.x & 7;             // batch group (XCD-aligned)
    const int hb = blockIdx.x >> 3;           // hidden part 0..31
    const int b0 = g << 5;
    const int j0 = hb << 4;
    int* myflag = flags + (g << 5) + hb;
    int* grpflags = flags + (g << 5);

    const int rr = tid >> 4;                  // reduce row 0..15
    const int jj = tid & 15;                  // reduce unit 0..15
    float c0 = 0.f, c1 = 0.f;
    float bias[4];
    bool dead = false;

    for (int l = 0; l < NL; ++l) {
        const half_t* inb = (l & 1) ? bufB : bufA;
        half_t* outb = (l & 1) ? bufA : bufB;

        __syncthreads();  // previous layer's LDS reads done before overwrite
        {   // stage fused weight slice: 64 gcols x K=1024 (ih|hh)
            int row = tid >> 2;
            int q = tid & 3;
            int gt = row >> 4, u = row & 15;
            size_t grow = (size_t)l * 2048 + gt * HID + (j0 + u);
            const float* src = (q < 2) ? (w_ih + grow * HID + (q << 8))
                                       : (w_hh + grow * HID + ((q - 2) << 8));
            int kbase = q << 8;
            #pragma unroll 8
            for (int i = 0; i < 64; ++i) {
                float4 v = *(const float4*)(src + (i << 2));
                int k = kbase + (i << 2);
                int byte = row * 2048 + ((k * 2) ^ ((row & 7) << 4));
                half4v hv = {(half_t)v.x, (half_t)v.y, (half_t)v.z, (half_t)v.w};
                *(half4v*)((char*)Wl + byte) = hv;
            }
        }
        #pragma unroll
        for (int gt = 0; gt < 4; ++gt)
            bias[gt] = b_ih[(size_t)l * 2048 + gt * HID + j0 + jj] +
                       b_hh[(size_t)l * 2048 + gt * HID + j0 + jj];
        c0 = c1 = 0.f;
        __syncthreads();

        const bool hpart = (wv >= 2);
        const int kc = wv << 8;

        for (int t = 0; t < TSEQ; ++t) {
            const int epoch = (l << 8) + t;

            // X(t) prefetch into registers: no cross-block dependency, so issue
            // BEFORE the spin; loads complete while we wait for peers.
            half8 xa[8], xb[8];
            if (!hpart) {
                const half_t* ar = inb + ((size_t)t * NBAT + b0 + (lane & 15)) * HID
                                   + kc + ((lane >> 4) << 3);
                #pragma unroll
                for (int kit = 0; kit < 8; ++kit) {
                    xa[kit] = ld_cg16(ar + (kit << 5));
                    xb[kit] = ld_cg16(ar + 16 * HID + (kit << 5));
                }
            }

            // acquire: wait for all 32 peers to have published h(t-1) (guarded)
            if (tid < 32 && !dead) {
                int guard = 0;
                while (__hip_atomic_load(grpflags + tid, __ATOMIC_RELAXED,
                                         __HIP_MEMORY_SCOPE_AGENT) < epoch) {
                    __builtin_amdgcn_s_sleep(2);
                    if (++guard > (1 << 20)) { dead = true; break; }
                }
            }
            __syncthreads();

            // GEMM: g[32 x 64gcols] = X[32 x 1024] . Wl^T, wave wv owns K-chunk
            f32x4 acc[2][4];
            #pragma unroll
            for (int m = 0; m < 2; ++m)
                #pragma unroll
                for (int n = 0; n < 4; ++n) acc[m][n] = (f32x4){0.f, 0.f, 0.f, 0.f};

            if (!hpart) {
                #pragma unroll
                for (int kit = 0; kit < 8; ++kit) {
                    #pragma unroll
                    for (int n = 0; n < 4; ++n) {
                        int row = (n << 4) + (lane & 15);
                        int k = kc + (kit << 5) + ((lane >> 4) << 3);
                        int byte = row * 2048 + ((k * 2) ^ ((row & 7) << 4));
                        half8 b = *(const half8*)((char*)Wl + byte);
                        acc[0][n] = __builtin_amdgcn_mfma_f32_16x16x32_f16(xa[kit], b, acc[0][n], 0, 0, 0);
                        acc[1][n] = __builtin_amdgcn_mfma_f32_16x16x32_f16(xb[kit], b, acc[1][n], 0, 0, 0);
                    }
                }
            } else if (t > 0) {
                const half_t* hr = outb + ((size_t)(t - 1) * NBAT + b0 + (lane & 15)) * HID
                                   + (kc - 512) + ((lane >> 4) << 3);
                #pragma unroll
                for (int kit = 0; kit < 8; ++kit) {
                    half8 a0 = ld_cg16(hr + (kit << 5));
                    half8 a1 = ld_cg16(hr + 16 * HID + (kit << 5));
                    #pragma unroll
                    for (int n = 0; n < 4; ++n) {
                        int row = (n << 4) + (lane & 15);
                        int k = kc + (kit << 5) + ((lane >> 4) << 3);
                        int byte = row * 2048 + ((k * 2) ^ ((row & 7) << 4));
                        half8 b = *(const half8*)((char*)Wl + byte);
                        acc[0][n] = __builtin_amdgcn_mfma_f32_16x16x32_f16(a0, b, acc[0][n], 0, 0, 0);
                        acc[1][n] = __builtin_amdgcn_mfma_f32_16x16x32_f16(a1, b, acc[1][n], 0, 0, 0);
                    }
                }
            }

            // reduce + gates, two 16-row phases; Pl XOR-swizzled (4-way -> 2-way)
            #pragma unroll
            for (int ph = 0; ph < 2; ++ph) {
                __syncthreads();
                #pragma unroll
                for (int n = 0; n < 4; ++n)
                    #pragma unroll
                    for (int r = 0; r < 4; ++r) {
                        int prow = wv * 16 + ((lane >> 4) << 2) + r;
                        int pcol = (n << 4) + (lane & 15);
                        Pl[prow * 64 + (pcol ^ ((((prow >> 2) ^ prow) & 1) << 4))] =
                            acc[ph][n][r];
                    }
                __syncthreads();
                float gs[4];
                #pragma unroll
                for (int gt = 0; gt < 4; ++gt) {
                    float s = bias[gt];
                    #pragma unroll
                    for (int w2 = 0; w2 < 4; ++w2) {
                        int rrow = w2 * 16 + rr;
                        int rcol = (gt << 4) + jj;
                        s += Pl[rrow * 64 + (rcol ^ ((((rrow >> 2) ^ rrow) & 1) << 4))];
                    }
                    gs[gt] = s;
                }
                float ig = sigmoidf_(gs[0]);
                float fg = sigmoidf_(gs[1]);
                float gg = tanhf_(gs[2]);
                float og = sigmoidf_(gs[3]);
                float& cc = ph ? c1 : c0;
                cc = fg * cc + ig * gg;
                float h = og * tanhf_(cc);
                st_cg2(outb + ((size_t)t * NBAT + (b0 + (ph << 4) + rr)) * HID + (j0 + jj), h);
            }
            // release: drain own h stores to coherence point, then bump flag
            asm volatile("s_waitcnt vmcnt(0)" ::: "memory");
            __syncthreads();
            if (tid == 0)
                __hip_atomic_store(myflag, epoch + 1, __ATOMIC_RELAXED,
                                   __HIP_MEMORY_SCOPE_AGENT);
        }
    }
}

// ---------------- decoder: out[b] = act[T-1][b][:] . dec_W + dec_b
__global__ __launch_bounds__(256) void k_dec(const half_t* __restrict__ act,
                                             const float* __restrict__ dW,
                                             const float* __restrict__ db,
                                             float* __restrict__ out) {
    int tid = threadIdx.x;
    int bl = tid >> 3, part = tid & 7;
    int b = (blockIdx.x << 5) + bl;
    const half_t* row = act + ((size_t)(TSEQ - 1) * NBAT + b) * HID + (part << 6);
    float s = 0.f;
    #pragma unroll
    for (int i = 0; i < 8; ++i) {
        half8 v = ld_cg16(row + (i << 3));   // coherent: bypass stale L1/L2
        const float* wp = dW + (part << 6) + (i << 3);
        #pragma unroll
        for (int u = 0; u < 8; ++u) s += (float)v[u] * wp[u];
    }
    #pragma unroll
    for (int off = 1; off < 8; off <<= 1) s += __shfl_xor(s, off, 64);
    if (part == 0) out[b] = s + db[0];
}

extern "C" void kernel_launch(void* const* d_in, const int* in_sizes, int n_in,
                              void* d_out, int out_size, void* d_ws, size_t ws_size,
                              hipStream_t stream) {
    const float* x = (const float*)d_in[0];
    const float* eW = (const float*)d_in[1];
    const float* eb = (const float*)d_in[2];
    const float* wih = (const float*)d_in[3];
    const float* whh = (const float*)d_in[4];
    const float* bih = (const float*)d_in[5];
    const float* bhh = (const float*)d_in[6];
    const float* dW = (const float*)d_in[7];
    const float* db = (const float*)d_in[8];
    float* out = (float*)d_out;

    const size_t BUF = (size_t)TSEQ * NBAT * HID * sizeof(half_t);  // 64 MB
    if (ws_size < 2 * BUF + 4096) return;  // insufficient workspace: fail loudly

    char* ws = (char*)d_ws;
    half_t* bufA = (half_t*)ws;
    half_t* bufB = (half_t*)(ws + BUF);
    int* flags = (int*)(ws + 2 * BUF);

    hipMemsetAsync(flags, 0, 256 * sizeof(int), stream);

    (void)hipFuncSetAttribute((const void*)k_embed,
                              hipFuncAttributeMaxDynamicSharedMemorySize, 147456);
    (void)hipFuncSetAttribute((const void*)k_rec,
                              hipFuncAttributeMaxDynamicSharedMemorySize, 147456);

    k_embed<<<1024, 256, 147456, stream>>>(x, eW, eb, bufA);

    void* args[] = { (void*)&wih, (void*)&whh, (void*)&bih, (void*)&bhh,
                     (void*)&bufA, (void*)&bufB, (void*)&flags };
    hipError_t ce = hipLaunchCooperativeKernel((const void*)k_rec, dim3(256), dim3(256),
                                               args, 147456, stream);
    if (ce != hipSuccess) {
        k_rec<<<256, 256, 147456, stream>>>(wih, whh, bih, bhh, bufA, bufB, flags);
    }

    k_dec<<<8, 256, 0, stream>>>(bufB, dW, db, out);
}